// Round 2
// baseline (211.606 us; speedup 1.0000x reference)
//
#include <hip/hip_runtime.h>

// Packed-sequence LSTM (B=4096, T=512, D=18, H=8) + Linear(8->1) head.
//
// Latency-bound recurrence. Layout: 8 lanes per sequence, lane j owns hidden
// unit j and computes ALL 4 of its gates (i,f,g,o) locally -> the cell update
// is lane-local and the ONLY cross-lane op per step is the h broadcast
// (8 ds_swizzle, one DS-latency hop, overlapped with next step's x-dot).
// Gate math in float2 pairs (i,f)/(g,o) to encourage v_pk_fma_f32.
// 8 seqs/wave64, grid=512 one-wave blocks -> <=1 wave/SIMD, no issue sharing.
// x rows prefetched 4 steps deep (9x float2) to cover ~900cy HBM latency.

namespace {

constexpr int NB = 4096;
constexpr int NT = 512;
constexpr int ND = 18;
constexpr int NH = 8;

__device__ __forceinline__ float fsig(float x) {
    return __builtin_amdgcn_rcpf(1.0f + __expf(-x));
}
__device__ __forceinline__ float ftanh(float x) {
    // tanh(x) = 1 - 2/(e^{2x}+1)
    return fmaf(-2.0f, __builtin_amdgcn_rcpf(1.0f + __expf(x + x)), 1.0f);
}
__device__ __forceinline__ float swz(float v, int imm) { return v; } // unused

__global__ __launch_bounds__(64, 1) void lstm_packed(
    const float* __restrict__ x, const int* __restrict__ lengths,
    const float* __restrict__ W_ih, const float* __restrict__ W_hh,
    const float* __restrict__ b_ih, const float* __restrict__ b_hh,
    const float* __restrict__ W_lin, const float* __restrict__ b_lin,
    float* __restrict__ out)
{
    const int w  = (int)threadIdx.x;    // 0..63
    const int sg = w >> 3;              // seq within wave (0..7)
    const int j  = w & 7;               // hidden unit owned by this lane
    const int b  = (int)blockIdx.x * 8 + sg;
    const int len = lengths[b];

    // torch gate rows: i=j, f=8+j, g=16+j, o=24+j
    const int ri = j, rf = 8 + j, rg = 16 + j, ro = 24 + j;

    // per-lane weights, packed (i,f) and (g,o) for pk-fma
    float2 wif[ND], wgo[ND];
#pragma unroll
    for (int k = 0; k < ND; ++k) {
        wif[k] = make_float2(W_ih[ri * ND + k], W_ih[rf * ND + k]);
        wgo[k] = make_float2(W_ih[rg * ND + k], W_ih[ro * ND + k]);
    }
    float2 hif[NH], hgo[NH];
#pragma unroll
    for (int k = 0; k < NH; ++k) {
        hif[k] = make_float2(W_hh[ri * NH + k], W_hh[rf * NH + k]);
        hgo[k] = make_float2(W_hh[rg * NH + k], W_hh[ro * NH + k]);
    }
    const float2 bif = make_float2(b_ih[ri] + b_hh[ri], b_ih[rf] + b_hh[rf]);
    const float2 bgo = make_float2(b_ih[rg] + b_hh[rg], b_ih[ro] + b_hh[ro]);
    float wl[NH];
#pragma unroll
    for (int k = 0; k < NH; ++k) wl[k] = W_lin[k];
    const float bl = b_lin[0];

    float h_all[NH];
#pragma unroll
    for (int k = 0; k < NH; ++k) h_all[k] = 0.0f;
    float c = 0.0f, hown = 0.0f;

    const float* xb = x + (size_t)b * (NT * ND);
    float* yb = out + (size_t)b * NT;

    // 4-deep prefetch of x rows (72B each as 9x float2; 8B aligned)
    float2 xf0[9], xf1[9], xf2[9], xf3[9];
    {
        const float2* r0 = (const float2*)(xb + 0 * ND);
        const float2* r1 = (const float2*)(xb + 1 * ND);
        const float2* r2 = (const float2*)(xb + 2 * ND);
        const float2* r3 = (const float2*)(xb + 3 * ND);
#pragma unroll
        for (int k = 0; k < 9; ++k) { xf0[k] = r0[k]; xf1[k] = r1[k]; xf2[k] = r2[k]; xf3[k] = r3[k]; }
    }

    auto step = [&](int tt, float2 (&xc)[9]) {
        const bool act = tt < len;

        // gate pre-activations: x part (independent of h -> fills DS shadow)
        float2 aif = bif, ago = bgo;
#pragma unroll
        for (int k = 0; k < 9; ++k) {
            const float xa = xc[k].x, xv = xc[k].y;
            aif.x = fmaf(xa, wif[2 * k].x, aif.x);
            aif.y = fmaf(xa, wif[2 * k].y, aif.y);
            ago.x = fmaf(xa, wgo[2 * k].x, ago.x);
            ago.y = fmaf(xa, wgo[2 * k].y, ago.y);
            aif.x = fmaf(xv, wif[2 * k + 1].x, aif.x);
            aif.y = fmaf(xv, wif[2 * k + 1].y, aif.y);
            ago.x = fmaf(xv, wgo[2 * k + 1].x, ago.x);
            ago.y = fmaf(xv, wgo[2 * k + 1].y, ago.y);
        }

        // refill this buffer with row tt+4 (clamped inside the sequence)
        {
            int r4 = tt + 4;
            r4 = (r4 < NT) ? r4 : (NT - 1);
            const float2* rr = (const float2*)(xb + (size_t)r4 * ND);
#pragma unroll
            for (int k = 0; k < 9; ++k) xc[k] = rr[k];
        }

        // h part: two parallel accumulator chains (4 deep each)
        float2 aif2 = make_float2(0.f, 0.f), ago2 = make_float2(0.f, 0.f);
#pragma unroll
        for (int k = 0; k < NH; k += 2) {
            aif.x  = fmaf(h_all[k],     hif[k].x,     aif.x);
            aif.y  = fmaf(h_all[k],     hif[k].y,     aif.y);
            ago.x  = fmaf(h_all[k],     hgo[k].x,     ago.x);
            ago.y  = fmaf(h_all[k],     hgo[k].y,     ago.y);
            aif2.x = fmaf(h_all[k + 1], hif[k + 1].x, aif2.x);
            aif2.y = fmaf(h_all[k + 1], hif[k + 1].y, aif2.y);
            ago2.x = fmaf(h_all[k + 1], hgo[k + 1].x, ago2.x);
            ago2.y = fmaf(h_all[k + 1], hgo[k + 1].y, ago2.y);
        }
        aif.x += aif2.x; aif.y += aif2.y; ago.x += ago2.x; ago.y += ago2.y;

        // activations (all lane-local)
        const float iv = fsig(aif.x);
        const float fv = fsig(aif.y);
        const float gv = ftanh(ago.x);
        const float ov = fsig(ago.y);
        const float cn = fmaf(fv, c, iv * gv);
        c = act ? cn : c;                 // freeze past length
        const float tc = ftanh(c);
        const float hn = ov * tc;
        hown = act ? hn : hown;

        // broadcast h within each 8-lane group: src = (lane & 0x18) | k
        // BitMode imm = (xor<<10)|(or<<5)|and = (k<<5)|0x18
        const int hb = __float_as_int(hown);
        h_all[0] = __int_as_float(__builtin_amdgcn_ds_swizzle(hb, 0x018));
        h_all[1] = __int_as_float(__builtin_amdgcn_ds_swizzle(hb, 0x038));
        h_all[2] = __int_as_float(__builtin_amdgcn_ds_swizzle(hb, 0x058));
        h_all[3] = __int_as_float(__builtin_amdgcn_ds_swizzle(hb, 0x078));
        h_all[4] = __int_as_float(__builtin_amdgcn_ds_swizzle(hb, 0x098));
        h_all[5] = __int_as_float(__builtin_amdgcn_ds_swizzle(hb, 0x0B8));
        h_all[6] = __int_as_float(__builtin_amdgcn_ds_swizzle(hb, 0x0D8));
        h_all[7] = __int_as_float(__builtin_amdgcn_ds_swizzle(hb, 0x0F8));

        // linear head (redundant across the 8 lanes; lane j==0 stores)
        float y = bl;
#pragma unroll
        for (int k = 0; k < NH; ++k) y = fmaf(h_all[k], wl[k], y);
        if (act && j == 0) yb[tt] = y;
    };

    for (int t = 0; t < len; t += 4) {
        step(t + 0, xf0);
        step(t + 1, xf1);
        step(t + 2, xf2);
        step(t + 3, xf3);
    }
}

} // namespace

extern "C" void kernel_launch(void* const* d_in, const int* in_sizes, int n_in,
                              void* d_out, int out_size, void* d_ws, size_t ws_size,
                              hipStream_t stream) {
    const float* x     = (const float*)d_in[0];
    const int*   lens  = (const int*)d_in[1];
    const float* W_ih  = (const float*)d_in[2];
    const float* W_hh  = (const float*)d_in[3];
    const float* b_ih  = (const float*)d_in[4];
    const float* b_hh  = (const float*)d_in[5];
    const float* W_lin = (const float*)d_in[6];
    const float* b_lin = (const float*)d_in[7];
    float* out = (float*)d_out;

    // zero the padded region (kernel only writes t < len)
    hipMemsetAsync(out, 0, (size_t)NB * NT * sizeof(float), stream);

    lstm_packed<<<NB / 8, 64, 0, stream>>>(x, lens, W_ih, W_hh, b_ih, b_hh,
                                           W_lin, b_lin, out);
}

// Round 3
// 156.527 us; speedup vs baseline: 1.3519x; 1.3519x over previous
//
#include <hip/hip_runtime.h>

// Packed-sequence LSTM (B=4096, T=512, D=18, H=8) + Linear(8->1) head.
//
// Latency-bound recurrence; the wall is the longest wave's per-step cost.
// Layout: 16 lanes/seq (4 seqs/wave, grid=1024 one-wave blocks -> 1 wave/SIMD).
// Lane (p,j): p=0 computes gates {i,g}, p=1 computes {f,o} for hidden unit j.
// ALL cross-lane ops are DPP row_ror (VALU latency, no DS pipe):
//   - gate exchange between halves: row_ror:8 (involution, direction-proof)
//   - h "broadcast": row_ror:1..7 of hown delivers h in rotated order; the
//     per-lane W_hh/W_lin copies are stored in that rotated order, using a
//     runtime DPP self-calibration probe (robust to ror direction convention).
// Weights are pinned in VGPRs via asm("+v") so the compiler cannot remat the
// loads into the loop (the R1/R2 failure mode: VGPR oversubscription -> the
// compiler re-loaded weights every step on the serial path).
// x rows prefetched 4 steps deep (9x float2) to cover HBM/L3 latency.

namespace {

constexpr int NB = 4096;
constexpr int NT = 512;
constexpr int ND = 18;
constexpr int NH = 8;

__device__ __forceinline__ float fsig(float x) {
    return __builtin_amdgcn_rcpf(1.0f + __expf(-x));
}
__device__ __forceinline__ float ftanh(float x) {
    // tanh(x) = 1 - 2/(e^{2x}+1); saturates correctly
    return fmaf(-2.0f, __builtin_amdgcn_rcpf(1.0f + __expf(x + x)), 1.0f);
}
template <int C>
__device__ __forceinline__ float fdpp(float v) {
    const int i = __float_as_int(v);
    return __int_as_float(__builtin_amdgcn_update_dpp(i, i, C, 0xF, 0xF, true));
}
__device__ __forceinline__ void pin(float& v) { asm volatile("" : "+v"(v)); }

__global__ __launch_bounds__(64, 1) void lstm_packed(
    const float* __restrict__ x, const int* __restrict__ lengths,
    const float* __restrict__ W_ih, const float* __restrict__ W_hh,
    const float* __restrict__ b_ih, const float* __restrict__ b_hh,
    const float* __restrict__ W_lin, const float* __restrict__ b_lin,
    float* __restrict__ out)
{
    const int w   = (int)threadIdx.x;   // 0..63
    const int grp = w >> 4;             // 4 seqs/wave
    const int l16 = w & 15;
    const int p   = l16 >> 3;           // half: 0 -> {i,g}, 1 -> {f,o}
    const int j   = l16 & 7;            // hidden unit
    const int b   = (int)blockIdx.x * 4 + grp;
    const int len = lengths[b];

    // torch gate rows: i=j, f=8+j, g=16+j, o=24+j
    const int rowA = j + (p ? 8 : 0);    // p0: i, p1: f
    const int rowB = j + (p ? 24 : 16);  // p0: g, p1: o

    // --- DPP self-calibration: which h-index does row_ror:r deliver here? ---
    // hown at lane m holds h_{m&7} (replicated across halves), so rotating the
    // probe value (lane&7) tells each lane exactly which h it will receive.
    int idx[8];
    idx[0] = j;
    idx[1] = __builtin_amdgcn_update_dpp(0, j, 0x121, 0xF, 0xF, true) & 7;
    idx[2] = __builtin_amdgcn_update_dpp(0, j, 0x122, 0xF, 0xF, true) & 7;
    idx[3] = __builtin_amdgcn_update_dpp(0, j, 0x123, 0xF, 0xF, true) & 7;
    idx[4] = __builtin_amdgcn_update_dpp(0, j, 0x124, 0xF, 0xF, true) & 7;
    idx[5] = __builtin_amdgcn_update_dpp(0, j, 0x125, 0xF, 0xF, true) & 7;
    idx[6] = __builtin_amdgcn_update_dpp(0, j, 0x126, 0xF, 0xF, true) & 7;
    idx[7] = __builtin_amdgcn_update_dpp(0, j, 0x127, 0xF, 0xF, true) & 7;

    // --- per-lane weights, pinned in VGPRs ---
    float wxA[ND], wxB[ND];
#pragma unroll
    for (int k = 0; k < ND; ++k) {
        wxA[k] = W_ih[rowA * ND + k];
        wxB[k] = W_ih[rowB * ND + k];
        pin(wxA[k]); pin(wxB[k]);
    }
    float whA[NH], whB[NH], wlp[NH];
#pragma unroll
    for (int r = 0; r < NH; ++r) {
        whA[r] = W_hh[rowA * NH + idx[r]];   // rotated order
        whB[r] = W_hh[rowB * NH + idx[r]];
        wlp[r] = W_lin[idx[r]];
        pin(whA[r]); pin(whB[r]); pin(wlp[r]);
    }
    float biasA = b_ih[rowA] + b_hh[rowA];
    float biasB = b_ih[rowB] + b_hh[rowB];
    float bl = b_lin[0];
    pin(biasA); pin(biasB); pin(bl);

    // state: c, hown (lane m holds h_{m&7}), hr = rotations of hown
    float hr[NH];
#pragma unroll
    for (int r = 0; r < NH; ++r) hr[r] = 0.0f;
    float c = 0.0f, hown = 0.0f;

    const float* xb = x + (size_t)b * (NT * ND);
    float* yb = out + (size_t)b * NT;

    // 4-deep register prefetch of x rows (72B = 9x float2, 8B-aligned)
    float2 xf0[9], xf1[9], xf2[9], xf3[9];
    {
        const float2* r0 = (const float2*)(xb + 0 * ND);
        const float2* r1 = (const float2*)(xb + 1 * ND);
        const float2* r2 = (const float2*)(xb + 2 * ND);
        const float2* r3 = (const float2*)(xb + 3 * ND);
#pragma unroll
        for (int k = 0; k < 9; ++k) { xf0[k] = r0[k]; xf1[k] = r1[k]; xf2[k] = r2[k]; xf3[k] = r3[k]; }
    }

    auto step = [&](int tt, float2 (&xf)[9]) {
        const bool act = tt < len;

        // x part of gate pre-activations (uses h-independent prefetched row)
        float aA = biasA, aB = biasB;
#pragma unroll
        for (int k = 0; k < 9; ++k) {
            const float xa = xf[k].x, xv = xf[k].y;
            aA = fmaf(xa, wxA[2 * k], aA);
            aB = fmaf(xa, wxB[2 * k], aB);
            aA = fmaf(xv, wxA[2 * k + 1], aA);
            aB = fmaf(xv, wxB[2 * k + 1], aB);
        }

        // refill this buffer with row tt+4 (clamped; x is [B,512,18])
        {
            int r4 = tt + 4;
            r4 = (r4 < NT) ? r4 : (NT - 1);
            const float2* rr = (const float2*)(xb + (size_t)r4 * ND);
#pragma unroll
            for (int k = 0; k < 9; ++k) xf[k] = rr[k];
        }

        // recurrent part from rotation registers (h_{t-1}), 2 chains
        float aA2 = 0.0f, aB2 = 0.0f;
#pragma unroll
        for (int r = 0; r < NH; r += 2) {
            aA  = fmaf(hr[r],     whA[r],     aA);
            aB  = fmaf(hr[r],     whB[r],     aB);
            aA2 = fmaf(hr[r + 1], whA[r + 1], aA2);
            aB2 = fmaf(hr[r + 1], whB[r + 1], aB2);
        }
        aA += aA2; aB += aB2;

        // activations: vA = sigma (i or f); vB = p0: tanh(g), p1: sigma(o)
        const float vA   = fsig(aA);
        const float argB = p ? aB : (aB + aB);
        const float sB   = fsig(argB);
        const float vB   = p ? sB : fmaf(2.0f, sB, -1.0f);

        // half exchange via row_ror:8 (p0 sends i*g, receives f; p1 vice versa)
        const float send1 = p ? vA : (vA * vB);
        const float ex1   = fdpp<0x128>(send1);
        const float f_    = p ? send1 : ex1;
        const float ig_   = p ? ex1 : send1;
        const float cn    = fmaf(f_, c, ig_);
        c = act ? cn : c;                       // freeze past length
        const float tc    = ftanh(c);
        const float ex2   = fdpp<0x128>(vB);    // p0 receives o
        const float o_    = p ? vB : ex2;
        const float hn    = o_ * tc;
        hown = act ? hn : hown;

        // rotations of h_t: feed the head now and the recurrent dot next step
        hr[0] = hown;
        hr[1] = fdpp<0x121>(hown);
        hr[2] = fdpp<0x122>(hown);
        hr[3] = fdpp<0x123>(hown);
        hr[4] = fdpp<0x124>(hown);
        hr[5] = fdpp<0x125>(hown);
        hr[6] = fdpp<0x126>(hown);
        hr[7] = fdpp<0x127>(hown);

        // linear head on h_t (redundant across lanes; lane 0 of group stores)
        float y = bl;
#pragma unroll
        for (int r = 0; r < NH; ++r) y = fmaf(hr[r], wlp[r], y);
        if (act && l16 == 0) yb[tt] = y;
    };

    for (int t = 0; t < len; t += 4) {
        step(t + 0, xf0);
        step(t + 1, xf1);
        step(t + 2, xf2);
        step(t + 3, xf3);
    }
}

} // namespace

extern "C" void kernel_launch(void* const* d_in, const int* in_sizes, int n_in,
                              void* d_out, int out_size, void* d_ws, size_t ws_size,
                              hipStream_t stream) {
    const float* x     = (const float*)d_in[0];
    const int*   lens  = (const int*)d_in[1];
    const float* W_ih  = (const float*)d_in[2];
    const float* W_hh  = (const float*)d_in[3];
    const float* b_ih  = (const float*)d_in[4];
    const float* b_hh  = (const float*)d_in[5];
    const float* W_lin = (const float*)d_in[6];
    const float* b_lin = (const float*)d_in[7];
    float* out = (float*)d_out;

    // zero the padded region (kernel only writes t < len)
    hipMemsetAsync(out, 0, (size_t)NB * NT * sizeof(float), stream);

    lstm_packed<<<NB / 4, 64, 0, stream>>>(x, lens, W_ih, W_hh, b_ih, b_hh,
                                           W_lin, b_lin, out);
}

// Round 5
// 145.654 us; speedup vs baseline: 1.4528x; 1.0746x over previous
//
#include <hip/hip_runtime.h>

// Packed-sequence LSTM (B=4096, T=512, D=18, H=8) + Linear(8->1) head.
//
// Latency-bound recurrence; wall = longest wave's per-step cost x 512.
// Layout: 16 lanes/seq (4 seqs/wave, grid=1024 one-wave blocks -> 1 wave/SIMD).
// Lane (p,j): p=0 computes gates {i,g}, p=1 {f,o} for hidden unit j. All
// cross-lane traffic is DPP row_ror (VALU latency): ror:8 gate exchange,
// ror:1..7 h-rotation with rotation-ordered weight copies (runtime DPP
// self-calibration makes the direction convention correctness-proof).
//
// R5 vs R4 (which raced: no waitcnt between LDS-DMA and ds_read — there is
// no __syncthreads anywhere to force a drain):
//  1. EXPLICIT counted s_waitcnt vmcnt(8) before each row readback (vmcnt(10)
//     after the 6-row prologue). 2 DMA ops/row, 5 rows in flight = 10 ops;
//     <=8 retires the oldest row. Stores in vmcnt only inflate the retire
//     count symmetrically -> the fixed count stays safe.
//  2. DMA issued UNCONDITIONALLY each step with the source row clamped to
//     NT-1, so the in-flight count never shrinks near the tail (a fixed
//     vmcnt immediate stays exact). Rows past len feed discarded math only
//     (act-masked state/stores).

namespace {

constexpr int NT = 512;
constexpr int ND = 18;

typedef float v2f __attribute__((ext_vector_type(2)));
typedef float v4f __attribute__((ext_vector_type(4)));

__device__ __forceinline__ float fsig(float x) {
    return __builtin_amdgcn_rcpf(1.0f + __expf(-x));
}
__device__ __forceinline__ float ftanh(float x) {
    // tanh(x) = 1 - 2/(e^{2x}+1); saturates correctly
    return fmaf(-2.0f, __builtin_amdgcn_rcpf(1.0f + __expf(x + x)), 1.0f);
}
template <int C>
__device__ __forceinline__ float fdpp(float v) {
    const int i = __float_as_int(v);
    return __int_as_float(__builtin_amdgcn_update_dpp(i, i, C, 0xF, 0xF, true));
}
__device__ __forceinline__ void gload_lds(const void* g, void* l) {
    __builtin_amdgcn_global_load_lds(
        (const __attribute__((address_space(1))) void*)g,
        (__attribute__((address_space(3))) void*)l,
        4, 0, 0);
}

__global__ __launch_bounds__(64, 1) void lstm_packed(
    const float* __restrict__ x, const int* __restrict__ lengths,
    const float* __restrict__ W_ih, const float* __restrict__ W_hh,
    const float* __restrict__ b_ih, const float* __restrict__ b_hh,
    const float* __restrict__ W_lin, const float* __restrict__ b_lin,
    float* __restrict__ out)
{
    // LDS ring, 8 distinct slots. Slot k holds row r (r%8==k):
    // A*: elems 0..15 of each of the 4 seqs (64 lanes x 4B DMA),
    // B*: elems 16..17 (lanes 0..7 x 4B DMA).
    __shared__ __align__(16) float A0[4][16], A1[4][16], A2[4][16], A3[4][16],
                                   A4[4][16], A5[4][16], A6[4][16], A7[4][16];
    __shared__ __align__(8)  float B0[4][2], B1[4][2], B2[4][2], B3[4][2],
                                   B4[4][2], B5[4][2], B6[4][2], B7[4][2];

    const int w   = (int)threadIdx.x;   // 0..63
    const int grp = w >> 4;             // seq within wave
    const int l16 = w & 15;
    const int p   = l16 >> 3;           // half: 0 -> {i,g}, 1 -> {f,o}
    const int j   = l16 & 7;            // hidden unit
    const int b   = (int)blockIdx.x * 4 + grp;
    const int len = lengths[b];
    const int lenmax = lengths[blockIdx.x * 4];  // sorted desc -> block max

    // torch gate rows: i=j, f=8+j, g=16+j, o=24+j
    const int rowA = j + (p ? 8 : 0);    // p0: i, p1: f
    const int rowB = j + (p ? 24 : 16);  // p0: g, p1: o

    // DPP self-calibration: which h-index does row_ror:r deliver to this lane?
    int idx[8];
    idx[0] = j;
    idx[1] = __builtin_amdgcn_update_dpp(0, j, 0x121, 0xF, 0xF, true) & 7;
    idx[2] = __builtin_amdgcn_update_dpp(0, j, 0x122, 0xF, 0xF, true) & 7;
    idx[3] = __builtin_amdgcn_update_dpp(0, j, 0x123, 0xF, 0xF, true) & 7;
    idx[4] = __builtin_amdgcn_update_dpp(0, j, 0x124, 0xF, 0xF, true) & 7;
    idx[5] = __builtin_amdgcn_update_dpp(0, j, 0x125, 0xF, 0xF, true) & 7;
    idx[6] = __builtin_amdgcn_update_dpp(0, j, 0x126, 0xF, 0xF, true) & 7;
    idx[7] = __builtin_amdgcn_update_dpp(0, j, 0x127, 0xF, 0xF, true) & 7;

    // per-lane weights as float2 pairs (v_pk_fma_f32 operands)
    v2f wxA[9], wxB[9];
    {
        const v2f* ra = (const v2f*)(W_ih + rowA * ND);  // 72B rows, 8B aligned
        const v2f* rb = (const v2f*)(W_ih + rowB * ND);
#pragma unroll
        for (int k = 0; k < 9; ++k) { wxA[k] = ra[k]; wxB[k] = rb[k]; }
    }
    v2f whA[4], whB[4], wl2[4];
#pragma unroll
    for (int r = 0; r < 4; ++r) {
        whA[r] = v2f{W_hh[rowA * 8 + idx[2 * r]], W_hh[rowA * 8 + idx[2 * r + 1]]};
        whB[r] = v2f{W_hh[rowB * 8 + idx[2 * r]], W_hh[rowB * 8 + idx[2 * r + 1]]};
        wl2[r] = v2f{W_lin[idx[2 * r]], W_lin[idx[2 * r + 1]]};
    }
    const float biasA = b_ih[rowA] + b_hh[rowA];
    const float biasB = b_ih[rowB] + b_hh[rowB];
    const float bl = b_lin[0];

    // Per-lane fixed part of the DMA source address (row term added per issue).
    // op1: lane -> seq w>>4, elem w&15. op2 (lanes 0..7): seq w>>1, elem 16+(w&1).
    const char* xc = (const char*)x;
    const unsigned laneA = (((unsigned)(blockIdx.x * 4 + (w >> 4)) * (NT * ND)) + (unsigned)(w & 15)) * 4u;
    const unsigned laneB = (((unsigned)(blockIdx.x * 4 + ((w & 7) >> 1)) * (NT * ND)) + 16u + (unsigned)(w & 1)) * 4u;
    const char* pA = xc + laneA;
    const char* pB = xc + laneB;

    // prologue: DMA rows 0..5 into slots 0..5 (12 vmem ops)
#define PRE(RR, AA, BB)                                          \
    gload_lds(pA + (RR * 72u), &AA[0][0]);                       \
    if (w < 8) gload_lds(pB + (RR * 72u), &BB[0][0]);
    PRE(0, A0, B0) PRE(1, A1, B1) PRE(2, A2, B2)
    PRE(3, A3, B3) PRE(4, A4, B4) PRE(5, A5, B5)
#undef PRE

    float* yb = out + (size_t)b * NT;

    // current row regs; row 0 needs the first 2 DMA ops retired (12-2=10)
    v4f Rq[4];
    v2f Rt;
    asm volatile("s_waitcnt vmcnt(10)" ::: "memory");
    {
        const v4f* arp = (const v4f*)&A0[grp][0];
        Rq[0] = arp[0]; Rq[1] = arp[1]; Rq[2] = arp[2]; Rq[3] = arp[3];
        Rt = *(const v2f*)&B0[grp][0];
    }

    v2f hp[4] = {v2f{0.f, 0.f}, v2f{0.f, 0.f}, v2f{0.f, 0.f}, v2f{0.f, 0.f}};
    float c = 0.0f, hown = 0.0f;

#define STEP(KK, AR, BR, AW, BW)                                              \
    {                                                                         \
        const int tt = t + KK;                                                \
        /* x-dot on row tt (pk-fma pairs; bias folded into accumulator) */    \
        v2f aAx = v2f{biasA, 0.0f}, aBx = v2f{biasB, 0.0f};                   \
        aAx = Rq[0].lo * wxA[0] + aAx;  aBx = Rq[0].lo * wxB[0] + aBx;        \
        aAx = Rq[0].hi * wxA[1] + aAx;  aBx = Rq[0].hi * wxB[1] + aBx;        \
        aAx = Rq[1].lo * wxA[2] + aAx;  aBx = Rq[1].lo * wxB[2] + aBx;        \
        aAx = Rq[1].hi * wxA[3] + aAx;  aBx = Rq[1].hi * wxB[3] + aBx;        \
        aAx = Rq[2].lo * wxA[4] + aAx;  aBx = Rq[2].lo * wxB[4] + aBx;        \
        aAx = Rq[2].hi * wxA[5] + aAx;  aBx = Rq[2].hi * wxB[5] + aBx;        \
        aAx = Rq[3].lo * wxA[6] + aAx;  aBx = Rq[3].lo * wxB[6] + aBx;        \
        aAx = Rq[3].hi * wxA[7] + aAx;  aBx = Rq[3].hi * wxB[7] + aBx;        \
        aAx = Rt * wxA[8] + aAx;        aBx = Rt * wxB[8] + aBx;              \
        /* refill row tt+1: wait for its DMA (oldest in flight), then read */ \
        asm volatile("s_waitcnt vmcnt(8)" ::: "memory");                      \
        {                                                                     \
            const v4f* arp = (const v4f*)&AR[grp][0];                         \
            Rq[0] = arp[0]; Rq[1] = arp[1]; Rq[2] = arp[2]; Rq[3] = arp[3];   \
            Rt = *(const v2f*)&BR[grp][0];                                    \
        }                                                                     \
        /* DMA row tt+6 (clamped source; unconditional -> uniform in-flight)*/\
        {                                                                     \
            const unsigned rr = (unsigned)((tt + 6 < NT) ? (tt + 6) : (NT - 1)) * 72u; \
            gload_lds(pA + rr, &AW[0][0]);                                    \
            if (w < 8) gload_lds(pB + rr, &BW[0][0]);                         \
        }                                                                     \
        /* recurrent dot from rotation pairs */                               \
        v2f aAh = hp[0] * whA[0];  v2f aBh = hp[0] * whB[0];                  \
        aAh = hp[1] * whA[1] + aAh; aBh = hp[1] * whB[1] + aBh;               \
        aAh = hp[2] * whA[2] + aAh; aBh = hp[2] * whB[2] + aBh;               \
        aAh = hp[3] * whA[3] + aAh; aBh = hp[3] * whB[3] + aBh;               \
        const float aA = (aAx.x + aAx.y) + (aAh.x + aAh.y);                   \
        const float aB = (aBx.x + aBx.y) + (aBh.x + aBh.y);                   \
        /* activations: vA = sigma(i|f); vB = p0: tanh(g), p1: sigma(o) */    \
        const float vA   = fsig(aA);                                          \
        const float argB = p ? aB : (aB + aB);                                \
        const float sB   = fsig(argB);                                        \
        const float vB   = p ? sB : fmaf(2.0f, sB, -1.0f);                    \
        /* half exchange via ror:8; cell update; freeze past length */        \
        const float send1 = p ? vA : (vA * vB);                               \
        const float ex1   = fdpp<0x128>(send1);                               \
        const float f_    = p ? send1 : ex1;                                  \
        const float ig_   = p ? ex1 : send1;                                  \
        const bool  act   = tt < len;                                         \
        const float cn    = fmaf(f_, c, ig_);                                 \
        c = act ? cn : c;                                                     \
        const float tc    = ftanh(c);                                         \
        const float ex2   = fdpp<0x128>(vB);                                  \
        const float o_    = p ? vB : ex2;                                     \
        const float hn    = o_ * tc;                                          \
        hown = act ? hn : hown;                                               \
        /* h rotations -> pairs (feed next step's h-dot and the head) */      \
        const float h1 = fdpp<0x121>(hown);                                   \
        const float h2 = fdpp<0x122>(hown);                                   \
        const float h3 = fdpp<0x123>(hown);                                   \
        const float h4 = fdpp<0x124>(hown);                                   \
        const float h5 = fdpp<0x125>(hown);                                   \
        const float h6 = fdpp<0x126>(hown);                                   \
        const float h7 = fdpp<0x127>(hown);                                   \
        hp[0] = v2f{hown, h1}; hp[1] = v2f{h2, h3};                           \
        hp[2] = v2f{h4, h5};   hp[3] = v2f{h6, h7};                           \
        /* linear head; one lane per seq stores */                            \
        v2f ya = hp[0] * wl2[0];                                              \
        ya = hp[1] * wl2[1] + ya;                                             \
        ya = hp[2] * wl2[2] + ya;                                             \
        ya = hp[3] * wl2[3] + ya;                                             \
        const float y = ya.x + ya.y + bl;                                     \
        if (act && l16 == 0) yb[tt] = y;                                      \
    }

    for (int t = 0; t < lenmax; t += 8) {
        STEP(0, A1, B1, A6, B6)
        STEP(1, A2, B2, A7, B7)
        STEP(2, A3, B3, A0, B0)
        STEP(3, A4, B4, A1, B1)
        STEP(4, A5, B5, A2, B2)
        STEP(5, A6, B6, A3, B3)
        STEP(6, A7, B7, A4, B4)
        STEP(7, A0, B0, A5, B5)
    }
#undef STEP
}

} // namespace

extern "C" void kernel_launch(void* const* d_in, const int* in_sizes, int n_in,
                              void* d_out, int out_size, void* d_ws, size_t ws_size,
                              hipStream_t stream) {
    const float* x     = (const float*)d_in[0];
    const int*   lens  = (const int*)d_in[1];
    const float* W_ih  = (const float*)d_in[2];
    const float* W_hh  = (const float*)d_in[3];
    const float* b_ih  = (const float*)d_in[4];
    const float* b_hh  = (const float*)d_in[5];
    const float* W_lin = (const float*)d_in[6];
    const float* b_lin = (const float*)d_in[7];
    float* out = (float*)d_out;

    // zero the padded region (kernel only writes t < len)
    hipMemsetAsync(out, 0, (size_t)4096 * NT * sizeof(float), stream);

    lstm_packed<<<1024, 64, 0, stream>>>(x, lens, W_ih, W_hh, b_ih, b_hh,
                                         W_lin, b_lin, out);
}

// Round 6
// 120.101 us; speedup vs baseline: 1.7619x; 1.2128x over previous
//
#include <hip/hip_runtime.h>

// Packed-sequence LSTM (B=4096, T=512, D=18, H=8) + Linear(8->1) head.
//
// Latency-bound recurrence; wall = longest wave's per-step cost x 512.
// 16 lanes/seq (4 seqs/wave, 1024 one-wave blocks = 1 wave/SIMD). Lane (p,j):
// p=0 computes {i,g}, p=1 {f,o} of hidden unit j; cross-lane = DPP row_ror
// only (ror:8 exchange, ror:1..7 h-rotation w/ rotation-ordered weights via
// runtime DPP self-calibration).
//
// R6 vs R5 (which stalled ~520cy/step on s_waitcnt: per-step vmcnt(8) with
// 3 vm-ops/step only tolerated ~2.7 steps of vm latency; per-step stores
// counted against the window):
//  - 32-slot A ring + 4 B-blocks (8 rows per 64-lane DMA): rows DMA'd
//    24 rows (3 iters) ahead of use.
//  - ONE s_waitcnt vmcnt(16) per 8-step iteration. Safety proof independent
//    of store-retirement order: if this iter's last A-DMA is outstanding,
//    >=17 younger LOADS are outstanding (loads retire in-order) -> count
//    >16 -> wait blocks. Verified for prologue iters 0-2 as well.
//  - Row t+8 (next iter's first) is read AFTER the next iter's wait
//    (REFILL_FIRST), not at step 7.
//  - Stores batched: 8 y-regs -> 2x dwordx4 per iter (scalar fallback in
//    each sequence's boundary iteration only).

namespace {

constexpr int NT = 512;
constexpr int ND = 18;

typedef float v2f __attribute__((ext_vector_type(2)));
typedef float v4f __attribute__((ext_vector_type(4)));

__device__ __forceinline__ float fsig(float x) {
    return __builtin_amdgcn_rcpf(1.0f + __expf(-x));
}
__device__ __forceinline__ float ftanh(float x) {
    // tanh(x) = 1 - 2/(e^{2x}+1); saturates correctly
    return fmaf(-2.0f, __builtin_amdgcn_rcpf(1.0f + __expf(x + x)), 1.0f);
}
template <int C>
__device__ __forceinline__ float fdpp(float v) {
    const int i = __float_as_int(v);
    return __int_as_float(__builtin_amdgcn_update_dpp(i, i, C, 0xF, 0xF, true));
}
__device__ __forceinline__ void gload_lds(const void* g, void* l) {
    __builtin_amdgcn_global_load_lds(
        (const __attribute__((address_space(1))) void*)g,
        (__attribute__((address_space(3))) void*)l,
        4, 0, 0);
}

__global__ __launch_bounds__(64, 1) void lstm_packed(
    const float* __restrict__ x, const int* __restrict__ lengths,
    const float* __restrict__ W_ih, const float* __restrict__ W_hh,
    const float* __restrict__ b_ih, const float* __restrict__ b_hh,
    const float* __restrict__ W_lin, const float* __restrict__ b_lin,
    float* __restrict__ out)
{
    // A ring: 32 named slots (row r -> slot r%32), each [seq][elem0..15].
    // B blocks: 4 named (iter I -> block I%4), each [row0..7][seq][elem16..17].
    __shared__ __align__(16) float
        A0[4][16],  A1[4][16],  A2[4][16],  A3[4][16],  A4[4][16],  A5[4][16],
        A6[4][16],  A7[4][16],  A8[4][16],  A9[4][16],  A10[4][16], A11[4][16],
        A12[4][16], A13[4][16], A14[4][16], A15[4][16], A16[4][16], A17[4][16],
        A18[4][16], A19[4][16], A20[4][16], A21[4][16], A22[4][16], A23[4][16],
        A24[4][16], A25[4][16], A26[4][16], A27[4][16], A28[4][16], A29[4][16],
        A30[4][16], A31[4][16];
    __shared__ __align__(16) float B0[8][4][2], B1[8][4][2], B2[8][4][2], B3[8][4][2];

    const int w   = (int)threadIdx.x;   // 0..63
    const int grp = w >> 4;             // seq within wave
    const int l16 = w & 15;
    const int p   = l16 >> 3;           // half: 0 -> {i,g}, 1 -> {f,o}
    const int j   = l16 & 7;            // hidden unit
    const int b   = (int)blockIdx.x * 4 + grp;
    const int len = lengths[b];
    const int lenmax = lengths[blockIdx.x * 4];  // sorted desc -> block max

    // torch gate rows: i=j, f=8+j, g=16+j, o=24+j
    const int rowA = j + (p ? 8 : 0);    // p0: i, p1: f
    const int rowB = j + (p ? 24 : 16);  // p0: g, p1: o

    // DPP self-calibration: which h-index does row_ror:r deliver to this lane?
    int idx[8];
    idx[0] = j;
    idx[1] = __builtin_amdgcn_update_dpp(0, j, 0x121, 0xF, 0xF, true) & 7;
    idx[2] = __builtin_amdgcn_update_dpp(0, j, 0x122, 0xF, 0xF, true) & 7;
    idx[3] = __builtin_amdgcn_update_dpp(0, j, 0x123, 0xF, 0xF, true) & 7;
    idx[4] = __builtin_amdgcn_update_dpp(0, j, 0x124, 0xF, 0xF, true) & 7;
    idx[5] = __builtin_amdgcn_update_dpp(0, j, 0x125, 0xF, 0xF, true) & 7;
    idx[6] = __builtin_amdgcn_update_dpp(0, j, 0x126, 0xF, 0xF, true) & 7;
    idx[7] = __builtin_amdgcn_update_dpp(0, j, 0x127, 0xF, 0xF, true) & 7;

    // per-lane weights as float2 pairs (v_pk_fma_f32 operands)
    v2f wxA[9], wxB[9];
    {
        const v2f* ra = (const v2f*)(W_ih + rowA * ND);  // 72B rows, 8B aligned
        const v2f* rb = (const v2f*)(W_ih + rowB * ND);
#pragma unroll
        for (int k = 0; k < 9; ++k) { wxA[k] = ra[k]; wxB[k] = rb[k]; }
    }
    v2f whA[4], whB[4], wl2[4];
#pragma unroll
    for (int r = 0; r < 4; ++r) {
        whA[r] = v2f{W_hh[rowA * 8 + idx[2 * r]], W_hh[rowA * 8 + idx[2 * r + 1]]};
        whB[r] = v2f{W_hh[rowB * 8 + idx[2 * r]], W_hh[rowB * 8 + idx[2 * r + 1]]};
        wl2[r] = v2f{W_lin[idx[2 * r]], W_lin[idx[2 * r + 1]]};
    }
    const float biasA = b_ih[rowA] + b_hh[rowA];
    const float biasB = b_ih[rowB] + b_hh[rowB];
    const float bl = b_lin[0];

    // DMA source bases.
    // A-op: lane -> seq w>>4, elem w&15 (row uniform).
    // B-op: lane -> row w>>3, seq (w>>1)&3, elem w&1 (row per-lane).
    const char* xc = (const char*)x;
    const unsigned laneA = (((unsigned)(blockIdx.x * 4 + (w >> 4)) * (NT * ND)) + (unsigned)(w & 15)) * 4u;
    const char* pA = xc + laneA;
    const unsigned bseqB = (unsigned)(blockIdx.x * 4) + (unsigned)((w >> 1) & 3);
    const unsigned laneB = (bseqB * (NT * ND) + 16u + (unsigned)(w & 1)) * 4u;
    const char* pB = xc + laneB;
    const unsigned rB0 = (unsigned)(w >> 3);   // per-lane row-in-block 0..7

    // prologue: B blocks for iters 0..2, then A rows 0..23 (27 load ops)
    gload_lds(pB + (0u  + rB0) * 72u, &B0[0][0][0]);
    gload_lds(pB + (8u  + rB0) * 72u, &B1[0][0][0]);
    gload_lds(pB + (16u + rB0) * 72u, &B2[0][0][0]);
#define PA(RR, AA) gload_lds(pA + (RR * 72u), &AA[0][0]);
    PA(0, A0)  PA(1, A1)  PA(2, A2)  PA(3, A3)  PA(4, A4)  PA(5, A5)
    PA(6, A6)  PA(7, A7)  PA(8, A8)  PA(9, A9)  PA(10, A10) PA(11, A11)
    PA(12, A12) PA(13, A13) PA(14, A14) PA(15, A15) PA(16, A16) PA(17, A17)
    PA(18, A18) PA(19, A19) PA(20, A20) PA(21, A21) PA(22, A22) PA(23, A23)
#undef PA

    float* yb = out + (size_t)b * NT;

    v4f Rq[4];
    v2f Rt;
    v2f hp[4] = {v2f{0.f, 0.f}, v2f{0.f, 0.f}, v2f{0.f, 0.f}, v2f{0.f, 0.f}};
    float c = 0.0f, hown = 0.0f;

#define WAIT16 asm volatile("s_waitcnt vmcnt(16)" ::: "memory");

#define READROW(AF, BR, EE)                                                   \
    {                                                                         \
        const v4f* arp = (const v4f*)&AF[grp][0];                             \
        Rq[0] = arp[0]; Rq[1] = arp[1]; Rq[2] = arp[2]; Rq[3] = arp[3];       \
        Rt = *(const v2f*)&BR[EE][grp][0];                                    \
    }

#define BDMA(BW)                                                              \
    {                                                                         \
        unsigned rb = (unsigned)t + 24u + rB0;                                \
        rb = (rb < NT) ? rb : (NT - 1);                                       \
        gload_lds(pB + rb * 72u, &BW[0][0][0]);                               \
    }

    // STEP KK: consume row t+KK (in Rq/Rt), refill row t+KK+1 from AR/BR[E],
    // DMA row t+24+KK into AW. STEPL: no refill.
#define STEPCORE(KK)                                                          \
        const int tt = t + KK;                                                \
        v2f aAx = v2f{biasA, 0.0f}, aBx = v2f{biasB, 0.0f};                   \
        aAx = Rq[0].lo * wxA[0] + aAx;  aBx = Rq[0].lo * wxB[0] + aBx;        \
        aAx = Rq[0].hi * wxA[1] + aAx;  aBx = Rq[0].hi * wxB[1] + aBx;        \
        aAx = Rq[1].lo * wxA[2] + aAx;  aBx = Rq[1].lo * wxB[2] + aBx;        \
        aAx = Rq[1].hi * wxA[3] + aAx;  aBx = Rq[1].hi * wxB[3] + aBx;        \
        aAx = Rq[2].lo * wxA[4] + aAx;  aBx = Rq[2].lo * wxB[4] + aBx;        \
        aAx = Rq[2].hi * wxA[5] + aAx;  aBx = Rq[2].hi * wxB[5] + aBx;        \
        aAx = Rq[3].lo * wxA[6] + aAx;  aBx = Rq[3].lo * wxB[6] + aBx;        \
        aAx = Rq[3].hi * wxA[7] + aAx;  aBx = Rq[3].hi * wxB[7] + aBx;        \
        aAx = Rt * wxA[8] + aAx;        aBx = Rt * wxB[8] + aBx;

#define STEPTAIL(KK)                                                          \
        v2f aAh = hp[0] * whA[0];  v2f aBh = hp[0] * whB[0];                  \
        aAh = hp[1] * whA[1] + aAh; aBh = hp[1] * whB[1] + aBh;               \
        aAh = hp[2] * whA[2] + aAh; aBh = hp[2] * whB[2] + aBh;               \
        aAh = hp[3] * whA[3] + aAh; aBh = hp[3] * whB[3] + aBh;               \
        const float aA = (aAx.x + aAx.y) + (aAh.x + aAh.y);                   \
        const float aB = (aBx.x + aBx.y) + (aBh.x + aBh.y);                   \
        const float vA   = fsig(aA);                                          \
        const float argB = p ? aB : (aB + aB);                                \
        const float sB   = fsig(argB);                                        \
        const float vB   = p ? sB : fmaf(2.0f, sB, -1.0f);                    \
        const float send1 = p ? vA : (vA * vB);                               \
        const float ex1   = fdpp<0x128>(send1);                               \
        const float f_    = p ? send1 : ex1;                                  \
        const float ig_   = p ? ex1 : send1;                                  \
        const bool  act   = tt < len;                                         \
        const float cn    = fmaf(f_, c, ig_);                                 \
        c = act ? cn : c;                                                     \
        const float tc    = ftanh(c);                                         \
        const float ex2   = fdpp<0x128>(vB);                                  \
        const float o_    = p ? vB : ex2;                                     \
        const float hn    = o_ * tc;                                          \
        hown = act ? hn : hown;                                               \
        const float h1 = fdpp<0x121>(hown);                                   \
        const float h2 = fdpp<0x122>(hown);                                   \
        const float h3 = fdpp<0x123>(hown);                                   \
        const float h4 = fdpp<0x124>(hown);                                   \
        const float h5 = fdpp<0x125>(hown);                                   \
        const float h6 = fdpp<0x126>(hown);                                   \
        const float h7 = fdpp<0x127>(hown);                                   \
        hp[0] = v2f{hown, h1}; hp[1] = v2f{h2, h3};                           \
        hp[2] = v2f{h4, h5};   hp[3] = v2f{h6, h7};                           \
        v2f ya = hp[0] * wl2[0];                                              \
        ya = hp[1] * wl2[1] + ya;                                             \
        ya = hp[2] * wl2[2] + ya;                                             \
        ya = hp[3] * wl2[3] + ya;                                             \
        y_##KK = ya.x + ya.y + bl;

#define STEP(KK, AR, BR, EE, AW)                                              \
    {                                                                         \
        STEPCORE(KK)                                                          \
        READROW(AR, BR, EE)                                                   \
        {                                                                     \
            const int rd = (tt + 24 < NT) ? (tt + 24) : (NT - 1);             \
            gload_lds(pA + (unsigned)rd * 72u, &AW[0][0]);                    \
        }                                                                     \
        STEPTAIL(KK)                                                          \
    }

#define STEPL(KK, AW)                                                         \
    {                                                                         \
        STEPCORE(KK)                                                          \
        {                                                                     \
            const int rd = (tt + 24 < NT) ? (tt + 24) : (NT - 1);             \
            gload_lds(pA + (unsigned)rd * 72u, &AW[0][0]);                    \
        }                                                                     \
        STEPTAIL(KK)                                                          \
    }

#define STORES                                                                \
    if (l16 == 0) {                                                           \
        if (t + 7 < len) {                                                    \
            *(v4f*)(yb + t)     = v4f{y_0, y_1, y_2, y_3};                    \
            *(v4f*)(yb + t + 4) = v4f{y_4, y_5, y_6, y_7};                    \
        } else {                                                              \
            if (t + 0 < len) yb[t + 0] = y_0;                                 \
            if (t + 1 < len) yb[t + 1] = y_1;                                 \
            if (t + 2 < len) yb[t + 2] = y_2;                                 \
            if (t + 3 < len) yb[t + 3] = y_3;                                 \
            if (t + 4 < len) yb[t + 4] = y_4;                                 \
            if (t + 5 < len) yb[t + 5] = y_5;                                 \
            if (t + 6 < len) yb[t + 6] = y_6;                                 \
            if (t + 7 < len) yb[t + 7] = y_7;                                 \
        }                                                                     \
    }

#define BODY(BR, BW, AF, R1, R2, R3, R4, R5, R6, R7, W0, W1, W2, W3, W4, W5, W6, W7) \
    {                                                                         \
        float y_0, y_1, y_2, y_3, y_4, y_5, y_6, y_7;                         \
        WAIT16                                                                \
        READROW(AF, BR, 0)                                                    \
        BDMA(BW)                                                              \
        STEP(0, R1, BR, 1, W0)                                                \
        STEP(1, R2, BR, 2, W1)                                                \
        STEP(2, R3, BR, 3, W2)                                                \
        STEP(3, R4, BR, 4, W3)                                                \
        STEP(4, R5, BR, 5, W4)                                                \
        STEP(5, R6, BR, 6, W5)                                                \
        STEP(6, R7, BR, 7, W6)                                                \
        STEPL(7, W7)                                                          \
        STORES                                                                \
    }

    int t = 0;
    while (t < lenmax) {
        BODY(B0, B3, A0,  A1,  A2,  A3,  A4,  A5,  A6,  A7,
                         A24, A25, A26, A27, A28, A29, A30, A31)
        t += 8; if (t >= lenmax) break;
        BODY(B1, B0, A8,  A9,  A10, A11, A12, A13, A14, A15,
                         A0,  A1,  A2,  A3,  A4,  A5,  A6,  A7)
        t += 8; if (t >= lenmax) break;
        BODY(B2, B1, A16, A17, A18, A19, A20, A21, A22, A23,
                         A8,  A9,  A10, A11, A12, A13, A14, A15)
        t += 8; if (t >= lenmax) break;
        BODY(B3, B2, A24, A25, A26, A27, A28, A29, A30, A31,
                         A16, A17, A18, A19, A20, A21, A22, A23)
        t += 8;
    }
#undef BODY
#undef STORES
#undef STEPL
#undef STEP
#undef STEPTAIL
#undef STEPCORE
#undef BDMA
#undef READROW
#undef WAIT16
}

} // namespace

extern "C" void kernel_launch(void* const* d_in, const int* in_sizes, int n_in,
                              void* d_out, int out_size, void* d_ws, size_t ws_size,
                              hipStream_t stream) {
    const float* x     = (const float*)d_in[0];
    const int*   lens  = (const int*)d_in[1];
    const float* W_ih  = (const float*)d_in[2];
    const float* W_hh  = (const float*)d_in[3];
    const float* b_ih  = (const float*)d_in[4];
    const float* b_hh  = (const float*)d_in[5];
    const float* W_lin = (const float*)d_in[6];
    const float* b_lin = (const float*)d_in[7];
    float* out = (float*)d_out;

    // zero the padded region (kernel only writes t < len)
    hipMemsetAsync(out, 0, (size_t)4096 * NT * sizeof(float), stream);

    lstm_packed<<<1024, 64, 0, stream>>>(x, lens, W_ih, W_hh, b_ih, b_hh,
                                         W_lin, b_lin, out);
}

// Round 7
// 85.734 us; speedup vs baseline: 2.4682x; 1.4009x over previous
//
#include <hip/hip_runtime.h>

// Packed-sequence LSTM (B=4096, T=512, D=18, H=8) + Linear(8->1) head.
//
// R7: producer/consumer wave split. The recurrence is issue-bound on its
// wave (R6: ~335cy/step of VALU issue while active); the x-gate dot
// (36 MACs + LDS reads + DMA bookkeeping) is h-independent, so it moves to
// a second wave. Block = 128 threads = 2 waves:
//   wave 1 (producer): R6's DMA machinery (A/B rings, counted vmcnt) +
//     computes xg[t][gate-pair] = W_ih.x_t + bias, 2 chunks (16 steps)
//     ahead, into a 4-buffer LDS ring.
//   wave 0 (consumer): the serial LSTM. Per step: 1 ds_read_b64 (its 2
//     gate pre-activations, prefetched one step ahead; chunk boundary pair
//     prefetched BEFORE the barrier), 8-unit h-dot, activations, DPP-only
//     cross-lane (ror:8 exchange, ror:1..7 h rotation, runtime-calibrated
//     rotated weight order), batched y stores.
// Sync: ONE raw s_barrier per 8-step chunk (NOT __syncthreads - that drains
// vmcnt and would kill the DMA pipeline) + producer lgkmcnt(0) before it;
// sched_barrier(0) fences code motion around barriers.
// vmcnt proof: 9 DMA ops/chunk, no stores on producer wave. At iter-c wait,
// outstanding = chunks {c+2, c+3} (18 ops); vmcnt(9) retires chunk c+2
// (issued 2 iters = ~2400cy ago > ~900cy HBM). Prologue: DMA c0..c2 (27),
// wait(18) retires c0; produce c0; wait(9) retires c1; produce c1; DMA c3.
// State freezing dropped: outputs past len are never stored, activations
// saturate (no NaN), so state updates run unmasked.

namespace {

constexpr int NT = 512;
constexpr int ND = 18;
constexpr float LOG2E = 1.4426950408889634f;

typedef float v2f __attribute__((ext_vector_type(2)));
typedef float v4f __attribute__((ext_vector_type(4)));

template <int C>
__device__ __forceinline__ float fdpp(float v) {
    const int i = __float_as_int(v);
    return __int_as_float(__builtin_amdgcn_update_dpp(i, i, C, 0xF, 0xF, true));
}
__device__ __forceinline__ void gload_lds(const void* g, void* l) {
    __builtin_amdgcn_global_load_lds(
        (const __attribute__((address_space(1))) void*)g,
        (__attribute__((address_space(3))) void*)l, 4, 0, 0);
}

__global__ __launch_bounds__(128, 1) void lstm_pc(
    const float* __restrict__ x, const int* __restrict__ lengths,
    const float* __restrict__ W_ih, const float* __restrict__ W_hh,
    const float* __restrict__ b_ih, const float* __restrict__ b_hh,
    const float* __restrict__ W_lin, const float* __restrict__ b_lin,
    float* __restrict__ out)
{
    // A ring: 32 row slots (row r -> slot r&31), [seq][elem0..15].
    // B ring: 4 chunk blocks, [row-in-chunk][seq][elem16..17] (linear = lane).
    // XG ring: 4 chunk buffers, [t-in-chunk][gate-pair][seq(+1 pad)] of v2f.
    __shared__ __align__(16) float Aring[32][4][16];
    __shared__ __align__(16) float Bring[4][8][4][2];
    __shared__ __align__(16) v2f   XG[4][8][16][5];

    const int tid  = (int)threadIdx.x;
    const int wav  = tid >> 6;          // 0 = consumer, 1 = producer
    const int w    = tid & 63;
    const int grp  = w >> 4;            // seq within block
    const int l16  = w & 15;
    const int p    = l16 >> 3;          // half: 0 -> {i,g}, 1 -> {f,o}
    const int j    = l16 & 7;           // hidden unit
    const int lenmax = lengths[blockIdx.x * 4];       // sorted desc
    const int nch  = (lenmax + 7) >> 3;
    const int rowA = j + (p ? 8 : 0);   // p0: i, p1: f
    const int rowB = j + (p ? 24 : 16); // p0: g, p1: o

    if (wav == 1) {
        // ============================ PRODUCER ============================
        v2f wxA[9], wxB[9];
        {
            const v2f* ra = (const v2f*)(W_ih + rowA * ND);
            const v2f* rb = (const v2f*)(W_ih + rowB * ND);
#pragma unroll
            for (int k = 0; k < 9; ++k) { wxA[k] = ra[k]; wxB[k] = rb[k]; }
        }
        const float biasA = b_ih[rowA] + b_hh[rowA];
        const float biasB = b_ih[rowB] + b_hh[rowB];

        // DMA source lanes (R6-proven): A-op: seq w>>4, elem w&15.
        // B-op: row w>>3, seq (w>>1)&3, elem 16+(w&1); dest linear = w.
        const char* xc = (const char*)x;
        const char* pA = xc + (size_t)((((unsigned)(blockIdx.x * 4 + (w >> 4)) * (NT * ND))
                                       + (unsigned)(w & 15)) * 4u);
        const char* pB = xc + (size_t)((((unsigned)(blockIdx.x * 4 + ((w >> 1) & 3)) * (NT * ND))
                                       + 16u + (unsigned)(w & 1)) * 4u);
        const unsigned rB0 = (unsigned)(w >> 3);

        auto dma_chunk = [&](int dd) {
            const int r0 = dd * 8;
#pragma unroll
            for (int k = 0; k < 8; ++k) {
                const int rr = (r0 + k < NT) ? (r0 + k) : (NT - 1);
                gload_lds(pA + (unsigned)rr * 72u, &Aring[(r0 + k) & 31][0][0]);
            }
            unsigned rb = (unsigned)r0 + rB0;
            rb = (rb < (unsigned)NT) ? rb : (unsigned)(NT - 1);
            gload_lds(pB + rb * 72u, &Bring[dd & 3][0][0][0]);
        };

        auto produce_chunk = [&](int cc) {
            const int s0 = (cc * 8) & 31;
            const int bf = cc & 3;
#pragma unroll
            for (int k = 0; k < 8; ++k) {
                const v4f* ap = (const v4f*)&Aring[s0 + k][grp][0];
                const v4f q0 = ap[0], q1 = ap[1], q2 = ap[2], q3 = ap[3];
                const v2f bt = *(const v2f*)&Bring[bf][k][grp][0];
                v2f aA = v2f{biasA, 0.f}, aB = v2f{biasB, 0.f};
                aA = q0.lo * wxA[0] + aA;  aB = q0.lo * wxB[0] + aB;
                aA = q0.hi * wxA[1] + aA;  aB = q0.hi * wxB[1] + aB;
                aA = q1.lo * wxA[2] + aA;  aB = q1.lo * wxB[2] + aB;
                aA = q1.hi * wxA[3] + aA;  aB = q1.hi * wxB[3] + aB;
                aA = q2.lo * wxA[4] + aA;  aB = q2.lo * wxB[4] + aB;
                aA = q2.hi * wxA[5] + aA;  aB = q2.hi * wxB[5] + aB;
                aA = q3.lo * wxA[6] + aA;  aB = q3.lo * wxB[6] + aB;
                aA = q3.hi * wxA[7] + aA;  aB = q3.hi * wxB[7] + aB;
                aA = bt    * wxA[8] + aA;  aB = bt    * wxB[8] + aB;
                XG[bf][k][l16][grp] = v2f{aA.x + aA.y, aB.x + aB.y};
            }
        };

        // prologue: DMA chunks 0..2 (27 ops), produce 0 and 1, DMA 3
        dma_chunk(0); dma_chunk(1); dma_chunk(2);
        asm volatile("s_waitcnt vmcnt(18)" ::: "memory");
        produce_chunk(0);
        asm volatile("s_waitcnt vmcnt(9)" ::: "memory");
        produce_chunk(1);
        dma_chunk(3);
        asm volatile("s_waitcnt lgkmcnt(0)" ::: "memory");
        __builtin_amdgcn_sched_barrier(0);
        __builtin_amdgcn_s_barrier();
        __builtin_amdgcn_sched_barrier(0);

        for (int c = 0; c < nch; ++c) {
            asm volatile("s_waitcnt vmcnt(9)" ::: "memory");
            dma_chunk(c + 4);
            produce_chunk(c + 2);
            asm volatile("s_waitcnt lgkmcnt(0)" ::: "memory");
            __builtin_amdgcn_sched_barrier(0);
            __builtin_amdgcn_s_barrier();
            __builtin_amdgcn_sched_barrier(0);
        }
    } else {
        // ============================ CONSUMER ============================
        const int len = lengths[blockIdx.x * 4 + grp];

        // DPP self-calibration: which h-index does row_ror:r deliver here?
        int idx[8];
        idx[0] = j;
        idx[1] = __builtin_amdgcn_update_dpp(0, j, 0x121, 0xF, 0xF, true) & 7;
        idx[2] = __builtin_amdgcn_update_dpp(0, j, 0x122, 0xF, 0xF, true) & 7;
        idx[3] = __builtin_amdgcn_update_dpp(0, j, 0x123, 0xF, 0xF, true) & 7;
        idx[4] = __builtin_amdgcn_update_dpp(0, j, 0x124, 0xF, 0xF, true) & 7;
        idx[5] = __builtin_amdgcn_update_dpp(0, j, 0x125, 0xF, 0xF, true) & 7;
        idx[6] = __builtin_amdgcn_update_dpp(0, j, 0x126, 0xF, 0xF, true) & 7;
        idx[7] = __builtin_amdgcn_update_dpp(0, j, 0x127, 0xF, 0xF, true) & 7;

        v2f whA[4], whB[4], wl2[4];
#pragma unroll
        for (int r = 0; r < 4; ++r) {
            whA[r] = v2f{W_hh[rowA * 8 + idx[2 * r]], W_hh[rowA * 8 + idx[2 * r + 1]]};
            whB[r] = v2f{W_hh[rowB * 8 + idx[2 * r]], W_hh[rowB * 8 + idx[2 * r + 1]]};
            wl2[r] = v2f{W_lin[idx[2 * r]], W_lin[idx[2 * r + 1]]};
        }
        const float bl = b_lin[0];
        // vB exponent scale: p0 computes tanh(g)=2*sigma(2g)-1, p1 sigma(o)
        const float Kp = p ? -LOG2E : -2.0f * LOG2E;

        float* yb = out + (size_t)(blockIdx.x * 4 + grp) * NT;

        v2f hp[4] = {v2f{0.f, 0.f}, v2f{0.f, 0.f}, v2f{0.f, 0.f}, v2f{0.f, 0.f}};
        float c_ = 0.0f, hown = 0.0f;

        __builtin_amdgcn_s_barrier();           // pairs with producer prologue
        __builtin_amdgcn_sched_barrier(0);

        v2f xgn = XG[0][0][l16][grp];           // chunk 0, step 0 (pre-written)

        for (int c = 0; c < nch; ++c) {
            const v2f* xgp  = &XG[c & 3][0][l16][grp];       // t stride = 80 v2f
            const v2f* xgp1 = &XG[(c + 1) & 3][0][l16][grp];
            const int t = c * 8;
            float y[8];
#pragma unroll
            for (int k = 0; k < 8; ++k) {
                const v2f xgc = xgn;
                xgn = (k < 7) ? xgp[(k + 1) * 80] : xgp1[0];  // next-step prefetch

                // recurrent dots
                v2f tA = hp[0] * whA[0];
                tA = hp[1] * whA[1] + tA;
                tA = hp[2] * whA[2] + tA;
                tA = hp[3] * whA[3] + tA;
                v2f tB = hp[0] * whB[0];
                tB = hp[1] * whB[1] + tB;
                tB = hp[2] * whB[2] + tB;
                tB = hp[3] * whB[3] + tB;
                const float aA = (xgc.x + tA.x) + tA.y;
                const float aB = (xgc.y + tB.x) + tB.y;

                // activations: vA = sigma(i|f); vB = p0 tanh(g), p1 sigma(o)
                const float vA = __builtin_amdgcn_rcpf(
                    1.0f + __builtin_amdgcn_exp2f(aA * -LOG2E));
                const float sB = __builtin_amdgcn_rcpf(
                    1.0f + __builtin_amdgcn_exp2f(aB * Kp));
                const float vB = p ? sB : fmaf(2.0f, sB, -1.0f);

                // half exchange via ror:8; unmasked cell update
                const float send1 = p ? vA : (vA * vB);
                const float ex1 = fdpp<0x128>(send1);
                const float f_ = p ? send1 : ex1;
                const float ig_ = p ? ex1 : send1;
                c_ = fmaf(f_, c_, ig_);
                const float tc = fmaf(-2.0f, __builtin_amdgcn_rcpf(
                    1.0f + __builtin_amdgcn_exp2f(c_ * (2.0f * LOG2E))), 1.0f);
                const float ex2 = fdpp<0x128>(vB);
                const float o_ = p ? vB : ex2;
                hown = o_ * tc;

                // h rotations -> pairs
                const float h1 = fdpp<0x121>(hown);
                const float h2 = fdpp<0x122>(hown);
                const float h3 = fdpp<0x123>(hown);
                const float h4 = fdpp<0x124>(hown);
                const float h5 = fdpp<0x125>(hown);
                const float h6 = fdpp<0x126>(hown);
                const float h7 = fdpp<0x127>(hown);
                hp[0] = v2f{hown, h1}; hp[1] = v2f{h2, h3};
                hp[2] = v2f{h4, h5};   hp[3] = v2f{h6, h7};

                // linear head
                v2f ya = hp[0] * wl2[0];
                ya = hp[1] * wl2[1] + ya;
                ya = hp[2] * wl2[2] + ya;
                ya = hp[3] * wl2[3] + ya;
                y[k] = (ya.x + ya.y) + bl;
            }

            if (l16 == 0) {
                if (t + 7 < len) {
                    *(v4f*)(yb + t)     = v4f{y[0], y[1], y[2], y[3]};
                    *(v4f*)(yb + t + 4) = v4f{y[4], y[5], y[6], y[7]};
                } else {
                    if (t + 0 < len) yb[t + 0] = y[0];
                    if (t + 1 < len) yb[t + 1] = y[1];
                    if (t + 2 < len) yb[t + 2] = y[2];
                    if (t + 3 < len) yb[t + 3] = y[3];
                    if (t + 4 < len) yb[t + 4] = y[4];
                    if (t + 5 < len) yb[t + 5] = y[5];
                    if (t + 6 < len) yb[t + 6] = y[6];
                    if (t + 7 < len) yb[t + 7] = y[7];
                }
            }
            __builtin_amdgcn_sched_barrier(0);
            __builtin_amdgcn_s_barrier();
            __builtin_amdgcn_sched_barrier(0);
        }
    }
}

} // namespace

extern "C" void kernel_launch(void* const* d_in, const int* in_sizes, int n_in,
                              void* d_out, int out_size, void* d_ws, size_t ws_size,
                              hipStream_t stream) {
    const float* x     = (const float*)d_in[0];
    const int*   lens  = (const int*)d_in[1];
    const float* W_ih  = (const float*)d_in[2];
    const float* W_hh  = (const float*)d_in[3];
    const float* b_ih  = (const float*)d_in[4];
    const float* b_hh  = (const float*)d_in[5];
    const float* W_lin = (const float*)d_in[6];
    const float* b_lin = (const float*)d_in[7];
    float* out = (float*)d_out;

    // zero the padded region (kernel only writes t < len)
    hipMemsetAsync(out, 0, (size_t)4096 * NT * sizeof(float), stream);

    lstm_pc<<<1024, 128, 0, stream>>>(x, lens, W_ih, W_hh, b_ih, b_hh,
                                      W_lin, b_lin, out);
}